// Round 7
// baseline (386.518 us; speedup 1.0000x reference)
//
#include <hip/hip_runtime.h>
#include <hip/hip_fp16.h>

// GCN: 3x GCNConv(relu) + global_mean_pool + FC, fp32 compute.
// R20: revert + bank. Evidence: dim-32 gather stuck at 45-55us across 3
// architectures (pull fused 55.6 / push 45.4 / push-deep 54.9) vs 51MB
// compulsory 8xXCD random row traffic -> pattern floor ~1.2TB/s effective;
// stop churning it. R19 post-mortem: occupancy/ILP don't move it (VALUBusy
// 9%, limiter is random-request throughput, not wave count).
//  - kernels reverted to best-measured set: R14 gather32<false> + 128-node
//    t2t3 (<43.7us each; R15 fusion measured 55.6 = 8us WORSE), R15 p2/layer1.
//  - NEW: mean-pool fused into gather-3 epilogue: split==0 lanes
//    unsafeAtomicAdd relu'd feats into gsum[512][32] (native fp32 atomics,
//    16k addrs); h3 write (6.4MB) + poolfc pass (6.4MB + launch) deleted.
//    gsum zeroed by p1's gptr blocks; fcfinish = 512 tiny wave reductions.
// Fixed per-iter overhead: harness 0xAA ws re-poison, 268 MB ~= 44 us.
// NOTE: integer inputs are int32 on device (NOT int64).

static constexpr int TPB = 256;
static constexpr int NB1 = 256;      // phase-1 blocks
static constexpr int NB_SCAN = 256;  // scan blocks
static constexpr int P2CAP = 6144;   // per-bucket LDS staging (ints)

// ---------- phase 1a: per-(bucket,block) histogram + (extra blocks) gptr+gsum0 ----------
__global__ void p1_hist_gptr_kernel(const int* __restrict__ dst, int* __restrict__ hist,
                                    int E, int chunk, int shift, int B,
                                    const int* __restrict__ batch, int* __restrict__ gstart,
                                    float* __restrict__ gsum, int n, int G) {
  int b = blockIdx.x, t = threadIdx.x;
  if (b >= NB1) {  // gptr role: gstart[g] = first i with batch[i] >= g (batch sorted)
    int i = (b - NB1) * TPB + t;
    if (i < G * 32) gsum[i] = 0.f;  // zero pool accumulators (G*32 = 16384 < n)
    if (i >= n) return;
    int bb = batch[i];
    int bp = (i == 0) ? -1 : batch[i - 1];
    for (int g = bp + 1; g <= bb; ++g) gstart[g] = i;
    if (i == n - 1)
      for (int g = bb + 1; g <= G; ++g) gstart[g] = n;
    return;
  }
  __shared__ int h[1024];  // B <= 1024 by construction
  for (int i = t; i < B; i += TPB) h[i] = 0;
  __syncthreads();
  int lo = b * chunk, hi = min(lo + chunk, E);
  for (int e = lo + t; e < hi; e += TPB) atomicAdd(&h[dst[e] >> shift], 1);
  __syncthreads();
  for (int i = t; i < B; i += TPB) hist[i * NB1 + b] = h[i];
}

// ---------- two-level exclusive scan ----------
__global__ void scan_partial_kernel(const int* __restrict__ a, int* __restrict__ bsum,
                                    int n, int seg) {
  int b = blockIdx.x, t = threadIdx.x;
  int lo = b * seg, hi = min(lo + seg, n);
  int acc = 0;
  for (int i = lo + t; i < hi; i += TPB) acc += a[i];
  __shared__ int red[TPB];
  red[t] = acc;
  __syncthreads();
  for (int st = TPB / 2; st > 0; st >>= 1) {
    if (t < st) red[t] += red[t + st];
    __syncthreads();
  }
  if (t == 0) bsum[b] = red[0];
}

__global__ void scan_emit_kernel(int* __restrict__ a, const int* __restrict__ bsum,
                                 int n, int seg) {
  int b = blockIdx.x, t = threadIdx.x;
  int lo = b * seg, hi = min(lo + seg, n);
  __shared__ int cs[TPB];
  __shared__ int s_run;
  cs[t] = (t < b) ? bsum[t] : 0;  // only blocks before me
  __syncthreads();
  for (int st = TPB / 2; st > 0; st >>= 1) {
    if (t < st) cs[t] += cs[t + st];
    __syncthreads();
  }
  if (t == 0) s_run = cs[0];
  __syncthreads();
  for (int base = lo; base < hi; base += TPB) {
    int i = base + t;
    int v = (i < hi) ? a[i] : 0;
    cs[t] = v;
    __syncthreads();
    for (int off = 1; off < TPB; off <<= 1) {
      int u = (t >= off) ? cs[t - off] : 0;
      __syncthreads();
      cs[t] += u;
      __syncthreads();
    }
    if (i < hi) a[i] = s_run + cs[t] - v;  // exclusive
    __syncthreads();
    if (t == 0) s_run += cs[TPB - 1];
    __syncthreads();
  }
}

// ---------- phase 1b: scatter packed edges into bucket-contiguous epk ----------
__global__ void p1_scatter_kernel(const int* __restrict__ src, const int* __restrict__ dst,
                                  const int* __restrict__ hist, unsigned int* __restrict__ epk,
                                  int E, int chunk, int shift, int srcbits, int B) {
  __shared__ int cur[1024];
  int b = blockIdx.x, t = threadIdx.x;
  for (int i = t; i < B; i += TPB) cur[i] = hist[i * NB1 + b];
  __syncthreads();
  int lo = b * chunk, hi = min(lo + chunk, E);
  int span1 = (1 << shift) - 1;
  for (int e = lo + t; e < hi; e += TPB) {
    int d = dst[e];
    int pos = atomicAdd(&cur[d >> shift], 1);
    epk[pos] = ((unsigned int)(d & span1) << srcbits) | (unsigned int)src[e];
  }
}

// ---------- phase 2: per-bucket counting sort + rowptr/dinv/u0 emit ----------
__global__ __launch_bounds__(TPB) void p2_sort_kernel(
    const unsigned int* __restrict__ epk, const int* __restrict__ hist,
    const float2* __restrict__ x2,
    int* __restrict__ rowptr, float* __restrict__ dinv, float2* __restrict__ u0,
    int* __restrict__ esrc, int N, int E, int shift, int srcbits, int B) {
  int bkt = blockIdx.x, t = threadIdx.x;
  int span = 1 << shift;  // == 256 == TPB for N <= 262144
  unsigned int smask = (1u << srcbits) - 1u;
  int nb = bkt << shift;
  int bstart = hist[bkt * NB1];
  int bend = (bkt + 1 < B) ? hist[(bkt + 1) * NB1] : E;
  int bsize = bend - bstart;
  __shared__ int cnt[256];
  __shared__ int ex[256];
  __shared__ int ldata[P2CAP];
  __shared__ int lsrc[P2CAP];
  bool stage = (bsize <= P2CAP);
  if (t < span) cnt[t] = 0;
  __syncthreads();
  if (stage) {
    for (int i = t; i < bsize; i += TPB) ldata[i] = (int)epk[bstart + i];  // coalesced
    __syncthreads();
    for (int i = t; i < bsize; i += TPB)
      atomicAdd(&cnt[((unsigned int)ldata[i]) >> srcbits], 1);
  } else {
    for (int e = bstart + t; e < bend; e += TPB) atomicAdd(&cnt[epk[e] >> srcbits], 1);
  }
  __syncthreads();
  int v = (t < span) ? cnt[t] : 0;
  ex[t] = v;
  __syncthreads();
  for (int off = 1; off < 256; off <<= 1) {  // Hillis-Steele inclusive
    int u = (t >= off) ? ex[t - off] : 0;
    __syncthreads();
    ex[t] += u;
    __syncthreads();
  }
  int excl = ex[t] - v;  // exclusive scan value
  int node = nb + t;
  if (t < span && node < N) {
    rowptr[node] = bstart + excl;
    float dv = rsqrtf((float)v + 1.0f);  // +1 self-loop
    dinv[node] = dv;
    float2 xv = x2[node];
    u0[node] = make_float2(xv.x * dv, xv.y * dv);
  }
  if (bkt == 0 && t == 0) rowptr[N] = E;
  __syncthreads();
  if (t < span) cnt[t] = stage ? excl : bstart + excl;  // reuse cnt as cursor
  __syncthreads();
  if (stage) {
    for (int i = t; i < bsize; i += TPB) {
      unsigned int p = (unsigned int)ldata[i];
      int pos = atomicAdd(&cnt[p >> srcbits], 1);
      lsrc[pos] = (int)(p & smask);
    }
    __syncthreads();
    for (int i = t; i < bsize; i += TPB) esrc[bstart + i] = lsrc[i];  // coalesced
  } else {
    for (int e = bstart + t; e < bend; e += TPB) {
      unsigned int p = epk[e];
      int pos = atomicAdd(&cnt[p >> srcbits], 1);
      esrc[pos] = (int)(p & smask);
    }
  }
}

// Fused layer 1: dim-2 fp32 gather (4-way edge split, unroll-2), shuffle-
// combine, each split computes 8 of 32 features of
// u1 = dinv * relu(dinv*(W1@U0) + b1), written fp16.
__global__ void layer1_kernel(const float2* __restrict__ u0, const int* __restrict__ rowptr,
                              const int* __restrict__ esrc, const float* __restrict__ W1,
                              const float* __restrict__ b1, const float* __restrict__ dinv,
                              __half* __restrict__ u1_16, int n) {
  int tid = blockIdx.x * blockDim.x + threadIdx.x;
  int i = tid >> 2, split = tid & 3;
  if (i >= n) return;
  float ax = 0.f, ay = 0.f;
  if (split == 0) {  // self-loop
    float2 s = u0[i];
    ax = s.x; ay = s.y;
  }
  int r0 = rowptr[i], r1 = rowptr[i + 1];
  int e = r0 + split;
  while (e + 4 < r1) {  // unroll-2: two rows in flight
    int s0 = esrc[e], s1 = esrc[e + 4];
    float2 v0 = u0[s0];
    float2 v1 = u0[s1];
    ax += v0.x + v1.x;
    ay += v0.y + v1.y;
    e += 8;
  }
  if (e < r1) {
    float2 v = u0[esrc[e]];
    ax += v.x; ay += v.y;
  }
  ax += __shfl_xor(ax, 1, 64); ay += __shfl_xor(ay, 1, 64);
  ax += __shfl_xor(ax, 2, 64); ay += __shfl_xor(ay, 2, 64);
  float di = dinv[i];
  int f0 = split * 8;
  union { float4 f4[1]; __half h[8]; } oh;
#pragma unroll
  for (int k = 0; k < 8; ++k) {
    int f = f0 + k;
    float hv = fmaxf(di * (W1[f * 2 + 0] * ax + W1[f * 2 + 1] * ay) + b1[f], 0.f);
    oh.h[k] = __float2half(di * hv);
  }
  *(float4*)&u1_16[(size_t)i * 32 + f0] = oh.f4[0];  // 16B-aligned
}

// Dim-32 fp16 pull gather, raw sums (layer 2's U1). 16 lanes/node: split =
// edge stripe (4), q = feature quad. Unroll-2 edge loop, shfl_xor combine.
__global__ void gather32_kernel(const float4* __restrict__ a16,
                                const int* __restrict__ rowptr, const int* __restrict__ esrc,
                                float4* __restrict__ out16, int n) {
  int tid = blockIdx.x * blockDim.x + threadIdx.x;
  int i = tid >> 4;
  int sub = tid & 15;
  int split = sub >> 2, q = sub & 3;
  if (i >= n) return;
  float acc[8] = {0.f, 0.f, 0.f, 0.f, 0.f, 0.f, 0.f, 0.f};
  auto addrow = [&](int s) {
    union { float4 f4; __half2 h2[4]; } u;
    u.f4 = a16[(size_t)s * 4 + q];
    float2 a0 = __half22float2(u.h2[0]);
    float2 a1 = __half22float2(u.h2[1]);
    float2 a2 = __half22float2(u.h2[2]);
    float2 a3 = __half22float2(u.h2[3]);
    acc[0] += a0.x; acc[1] += a0.y; acc[2] += a1.x; acc[3] += a1.y;
    acc[4] += a2.x; acc[5] += a2.y; acc[6] += a3.x; acc[7] += a3.y;
  };
  if (split == 0) addrow(i);  // self-loop
  int r0 = rowptr[i], r1 = rowptr[i + 1];
  int e = r0 + split;
  if (e < r1) {  // software-pipelined
    int snext = esrc[e];
    for (e += 4; e < r1; e += 4) {
      int scur = snext;
      snext = esrc[e];
      addrow(scur);
    }
    addrow(snext);
  }
#pragma unroll
  for (int k = 0; k < 8; ++k) acc[k] += __shfl_xor(acc[k], 4, 64);
#pragma unroll
  for (int k = 0; k < 8; ++k) acc[k] += __shfl_xor(acc[k], 8, 64);
  if (split != 0) return;
  union { float4 f4; __half2 h2[4]; } o;
  o.h2[0] = __floats2half2_rn(acc[0], acc[1]);
  o.h2[1] = __floats2half2_rn(acc[2], acc[3]);
  o.h2[2] = __floats2half2_rn(acc[4], acc[5]);
  o.h2[3] = __floats2half2_rn(acc[6], acc[7]);
  out16[(size_t)i * 4 + q] = o.f4;
}

// Dim-32 fp16 pull gather for layer 3 with relu epilogue FUSED WITH POOL:
// h3 = relu(di*acc + b3) is never written; split==0 lanes atomically add
// their 8 features into gsum[batch[i]][q*8..]. Native fp32 atomics (16k
// addresses, ~200 adds each).
__global__ void gather32pool_kernel(const float4* __restrict__ a16,
                                    const int* __restrict__ rowptr,
                                    const int* __restrict__ esrc,
                                    const float* __restrict__ dinv,
                                    const float* __restrict__ b,
                                    const int* __restrict__ batch,
                                    float* __restrict__ gsum, int n) {
  int tid = blockIdx.x * blockDim.x + threadIdx.x;
  int i = tid >> 4;
  int sub = tid & 15;
  int split = sub >> 2, q = sub & 3;
  if (i >= n) return;
  float acc[8] = {0.f, 0.f, 0.f, 0.f, 0.f, 0.f, 0.f, 0.f};
  auto addrow = [&](int s) {
    union { float4 f4; __half2 h2[4]; } u;
    u.f4 = a16[(size_t)s * 4 + q];
    float2 a0 = __half22float2(u.h2[0]);
    float2 a1 = __half22float2(u.h2[1]);
    float2 a2 = __half22float2(u.h2[2]);
    float2 a3 = __half22float2(u.h2[3]);
    acc[0] += a0.x; acc[1] += a0.y; acc[2] += a1.x; acc[3] += a1.y;
    acc[4] += a2.x; acc[5] += a2.y; acc[6] += a3.x; acc[7] += a3.y;
  };
  if (split == 0) addrow(i);  // self-loop
  int r0 = rowptr[i], r1 = rowptr[i + 1];
  int e = r0 + split;
  if (e < r1) {  // software-pipelined
    int snext = esrc[e];
    for (e += 4; e < r1; e += 4) {
      int scur = snext;
      snext = esrc[e];
      addrow(scur);
    }
    addrow(snext);
  }
#pragma unroll
  for (int k = 0; k < 8; ++k) acc[k] += __shfl_xor(acc[k], 4, 64);
#pragma unroll
  for (int k = 0; k < 8; ++k) acc[k] += __shfl_xor(acc[k], 8, 64);
  if (split != 0) return;
  float di = dinv[i];
  const float4 bv0 = ((const float4*)b)[2 * q];
  const float4 bv1 = ((const float4*)b)[2 * q + 1];
  acc[0] = fmaxf(di * acc[0] + bv0.x, 0.f);
  acc[1] = fmaxf(di * acc[1] + bv0.y, 0.f);
  acc[2] = fmaxf(di * acc[2] + bv0.z, 0.f);
  acc[3] = fmaxf(di * acc[3] + bv0.w, 0.f);
  acc[4] = fmaxf(di * acc[4] + bv1.x, 0.f);
  acc[5] = fmaxf(di * acc[5] + bv1.y, 0.f);
  acc[6] = fmaxf(di * acc[6] + bv1.z, 0.f);
  acc[7] = fmaxf(di * acc[7] + bv1.w, 0.f);
  float* gp = &gsum[(size_t)batch[i] * 32 + q * 8];
#pragma unroll
  for (int k = 0; k < 8; ++k) unsafeAtomicAdd(&gp[k], acc[k]);
}

// Fused layer-2+3 transform, register-tiled, 128 nodes/block; U1 fp16 in,
// g3 (dinv-prescaled) fp16 out.
__global__ __launch_bounds__(TPB) void t2t3_kernel(
    const float4* __restrict__ U1h, const float* __restrict__ W2, const float* __restrict__ b2,
    const float* __restrict__ W3, const float* __restrict__ dinv,
    __half* __restrict__ g3_16, int n) {
  constexpr int SN = 136;               // node-dim stride (16B-aligned fragments)
  __shared__ float U1l[32 * SN];        // [j][node]
  __shared__ float h2l[64 * SN];        // [k][node]
  __shared__ float W2l[32 * 68];        // [j][k], stride 68
  __shared__ float W3l[64 * 36];        // [j][k], stride 36
  __shared__ float dil[128];
  int t = threadIdx.x;
  int base = blockIdx.x * 128;
  for (int idx = t; idx < 2048; idx += TPB) {
    int k = idx >> 5, j = idx & 31;
    W2l[j * 68 + k] = W2[idx];
  }
  for (int idx = t; idx < 2048; idx += TPB) {
    int k = idx >> 6, j = idx & 63;
    W3l[j * 36 + k] = W3[idx];
  }
  if (t < 128) dil[t] = (base + t < n) ? dinv[base + t] : 0.f;
  for (int it = 0; it < 2; ++it) {
    int idx = it * 256 + t;
    int nl = idx >> 2, j0 = (idx & 3) * 8;
    int node = base + nl;
    union { float4 f4; __half2 h2[4]; } u;
    u.f4 = (node < n) ? U1h[(size_t)node * 4 + (idx & 3)]
                      : make_float4(0.f, 0.f, 0.f, 0.f);
#pragma unroll
    for (int k = 0; k < 4; ++k) {
      float2 p = __half22float2(u.h2[k]);
      U1l[(j0 + 2 * k + 0) * SN + nl] = p.x;
      U1l[(j0 + 2 * k + 1) * SN + nl] = p.y;
    }
  }
  __syncthreads();
  {  // phase 1: h2l[k][n] over 128n x 64k; thread 8n x 4k
    int a = t & 15, bb = t >> 4;
    int n0 = a * 8, k0 = bb * 4;
    float acc[4][8];
#pragma unroll
    for (int kk = 0; kk < 4; ++kk)
#pragma unroll
      for (int nn = 0; nn < 8; ++nn) acc[kk][nn] = 0.f;
#pragma unroll 8
    for (int j = 0; j < 32; ++j) {
      float4 ua = *(const float4*)&U1l[j * SN + n0];
      float4 ub = *(const float4*)&U1l[j * SN + n0 + 4];
      float4 w = *(const float4*)&W2l[j * 68 + k0];
      float un[8] = {ua.x, ua.y, ua.z, ua.w, ub.x, ub.y, ub.z, ub.w};
      float wk[4] = {w.x, w.y, w.z, w.w};
#pragma unroll
      for (int kk = 0; kk < 4; ++kk)
#pragma unroll
        for (int nn = 0; nn < 8; ++nn) acc[kk][nn] += un[nn] * wk[kk];
    }
    float4 bv = ((const float4*)b2)[bb];
    float bk[4] = {bv.x, bv.y, bv.z, bv.w};
#pragma unroll
    for (int kk = 0; kk < 4; ++kk) {
      float o[8];
#pragma unroll
      for (int nn = 0; nn < 8; ++nn)
        o[nn] = fmaxf(dil[n0 + nn] * acc[kk][nn] + bk[kk], 0.f);
      *(float4*)&h2l[(k0 + kk) * SN + n0] = make_float4(o[0], o[1], o[2], o[3]);
      *(float4*)&h2l[(k0 + kk) * SN + n0 + 4] = make_float4(o[4], o[5], o[6], o[7]);
    }
  }
  __syncthreads();
  {  // phase 2: g3[n][k] over 128n x 32k; thread 8n x 2k
    int a = t & 15, bb = t >> 4;
    int n0 = a * 8, k0 = bb * 2;
    float acc[2][8];
#pragma unroll
    for (int kk = 0; kk < 2; ++kk)
#pragma unroll
      for (int nn = 0; nn < 8; ++nn) acc[kk][nn] = 0.f;
#pragma unroll 8
    for (int j = 0; j < 64; ++j) {
      float4 ua = *(const float4*)&h2l[j * SN + n0];
      float4 ub = *(const float4*)&h2l[j * SN + n0 + 4];
      float w0 = W3l[j * 36 + k0];
      float w1 = W3l[j * 36 + k0 + 1];
      float un[8] = {ua.x, ua.y, ua.z, ua.w, ub.x, ub.y, ub.z, ub.w};
#pragma unroll
      for (int nn = 0; nn < 8; ++nn) {
        acc[0][nn] += un[nn] * w0;
        acc[1][nn] += un[nn] * w1;
      }
    }
#pragma unroll
    for (int nn = 0; nn < 8; ++nn) {
      int node = base + n0 + nn;
      if (node < n) {
        float di = dil[n0 + nn];
        __half2 hv = __floats2half2_rn(di * acc[0][nn], di * acc[1][nn]);
        *(__half2*)&g3_16[(size_t)node * 32 + k0] = hv;
      }
    }
  }
}

// Finisher: out[g] = dot(gsum[g]/cnt, Wfc) + bfc. One wave per graph.
__global__ void fcfinish_kernel(const float* __restrict__ gsum, const int* __restrict__ gstart,
                                const float* __restrict__ Wfc, const float* __restrict__ bfc,
                                float* __restrict__ out) {
  int gi = blockIdx.x;
  int t = threadIdx.x;
  if (t >= 32) return;
  float cnt = fmaxf((float)(gstart[gi + 1] - gstart[gi]), 1.f);
  float v = (gsum[(size_t)gi * 32 + t] / cnt) * Wfc[t];
  for (int o = 16; o; o >>= 1) v += __shfl_down(v, o, 32);
  if (t == 0) out[gi] = v + bfc[0];
}

extern "C" void kernel_launch(void* const* d_in, const int* in_sizes, int n_in,
                              void* d_out, int out_size, void* d_ws, size_t ws_size,
                              hipStream_t stream) {
  const float* x     = (const float*)d_in[0];
  const int*   ei    = (const int*)d_in[1];  // int32 on device
  const int*   batch = (const int*)d_in[2];
  const float* W1    = (const float*)d_in[3];
  const float* b1    = (const float*)d_in[4];
  const float* W2    = (const float*)d_in[5];
  const float* b2    = (const float*)d_in[6];
  const float* W3    = (const float*)d_in[7];
  const float* b3    = (const float*)d_in[8];
  const float* Wfc   = (const float*)d_in[9];
  const float* bfc   = (const float*)d_in[10];
  float* out = (float*)d_out;

  const int N = in_sizes[0] / 2;
  const int E = in_sizes[1] / 2;
  const int G = out_size;  // 512
  const int* src = ei;
  const int* dst = ei + E;

  // Bucket geometry: span = 1<<shift, B <= 1024, span <= 256 (p2 LDS width).
  int shift = 8;
  while ((((N + (1 << shift) - 1) >> shift)) > 1024) ++shift;
  const int B = (N + (1 << shift) - 1) >> shift;
  const int srcbits = 32 - shift;
  const int chunkE = (E + NB1 - 1) / NB1;
  const int M = B * NB1;
  const int segM = (M + NB_SCAN - 1) / NB_SCAN;

  char* ws = (char*)d_ws;
  size_t off = 0;
  auto alloc = [&](size_t bytes) -> char* {
    char* p = ws + off;
    off += (bytes + 255) & ~(size_t)255;
    return p;
  };
  float*        dinv   = (float*)alloc((size_t)N * 4);
  int*          rowptr = (int*)alloc((size_t)(N + 1) * 4);
  int*          esrc   = (int*)alloc((size_t)E * 4);
  int*          gstart = (int*)alloc((size_t)(G + 1) * 4);
  int*          hist   = (int*)alloc((size_t)M * 4);
  int*          bsum   = (int*)alloc((size_t)NB_SCAN * 4);
  unsigned int* epk    = (unsigned int*)alloc((size_t)E * 4);
  float2*       u0     = (float2*)alloc((size_t)N * 8);
  __half*       u1_16  = (__half*)alloc((size_t)N * 32 * 2);
  __half*       U1h    = (__half*)alloc((size_t)N * 32 * 2);
  __half*       g3_16  = (__half*)alloc((size_t)N * 32 * 2);
  float*        gsum   = (float*)alloc((size_t)G * 32 * 4);

  // --- structure build: bucketed counting sort (no global atomics) ---
  const int gptrBlocks = (N + TPB - 1) / TPB;
  p1_hist_gptr_kernel<<<NB1 + gptrBlocks, TPB, 0, stream>>>(dst, hist, E, chunkE, shift, B,
                                                            batch, gstart, gsum, N, G);
  scan_partial_kernel<<<NB_SCAN, TPB, 0, stream>>>(hist, bsum, M, segM);
  scan_emit_kernel<<<NB_SCAN, TPB, 0, stream>>>(hist, bsum, M, segM);
  p1_scatter_kernel<<<NB1, TPB, 0, stream>>>(src, dst, hist, epk, E, chunkE, shift, srcbits, B);
  p2_sort_kernel<<<B, TPB, 0, stream>>>(epk, hist, (const float2*)x, rowptr, dinv, u0, esrc,
                                        N, E, shift, srcbits, B);

  // --- layer 1: fused dim-2 gather + transform (fp16 out) ---
  layer1_kernel<<<((size_t)N * 4 + TPB - 1) / TPB, TPB, 0, stream>>>(
      u0, rowptr, esrc, W1, b1, dinv, u1_16, N);

  // --- layer 2: dim-32 pull gather -> raw sums U1h, then 128-node t2t3 -> g3 ---
  gather32_kernel<<<((size_t)N * 16 + TPB - 1) / TPB, TPB, 0, stream>>>(
      (const float4*)u1_16, rowptr, esrc, (float4*)U1h, N);
  t2t3_kernel<<<(N + 127) / 128, TPB, 0, stream>>>(
      (const float4*)U1h, W2, b2, W3, dinv, g3_16, N);

  // --- layer 3: dim-32 pull gather + relu epilogue + fused mean-pool ---
  gather32pool_kernel<<<((size_t)N * 16 + TPB - 1) / TPB, TPB, 0, stream>>>(
      (const float4*)g3_16, rowptr, esrc, dinv, b3, batch, gsum, N);

  // --- fc finisher ---
  fcfinish_kernel<<<G, 64, 0, stream>>>(gsum, gstart, Wfc, bfc, out);
}

// Round 8
// 213.685 us; speedup vs baseline: 1.8088x; 1.8088x over previous
//
#include <hip/hip_runtime.h>
#include <hip/hip_fp16.h>

// GCN: 3x GCNConv(relu) + global_mean_pool + FC, fp32 compute.
// R21: clean revert. R20's fused pool was a disaster (gather32pool 215us):
// 3.2M device-scope fp32 atomics onto 16k addrs -> WRITE_SIZE 6.25->100MB
// (32B/atomic) + ~200-way same-address serialization at L2. LESSON: dense
// reductions never via global atomics.
// Config = best-measured components: pull gather32 (raw) + gather32epi (relu,
// h3 out) + 128-node t2t3 + R15 poolfc (half2, 16 nodes in flight); unroll-2
// edge loops; R13 structure build untouched.
// Gather floor evidence (R15/R17/R19): 3 architectures converge 45-55us for
// the 51MB 8xXCD-replicated random row traffic -> at pattern floor.
// Fixed per-iter overhead: harness 0xAA ws re-poison, 268 MB ~= 44 us.
// NOTE: integer inputs are int32 on device (NOT int64).

static constexpr int TPB = 256;
static constexpr int NB1 = 256;      // phase-1 blocks
static constexpr int NB_SCAN = 256;  // scan blocks
static constexpr int P2CAP = 6144;   // per-bucket LDS staging (ints)

// ---------- phase 1a: per-(bucket,block) histogram + (extra blocks) gptr ----------
__global__ void p1_hist_gptr_kernel(const int* __restrict__ dst, int* __restrict__ hist,
                                    int E, int chunk, int shift, int B,
                                    const int* __restrict__ batch, int* __restrict__ gstart,
                                    int n, int G) {
  int b = blockIdx.x, t = threadIdx.x;
  if (b >= NB1) {  // gptr role: gstart[g] = first i with batch[i] >= g (batch sorted)
    int i = (b - NB1) * TPB + t;
    if (i >= n) return;
    int bb = batch[i];
    int bp = (i == 0) ? -1 : batch[i - 1];
    for (int g = bp + 1; g <= bb; ++g) gstart[g] = i;
    if (i == n - 1)
      for (int g = bb + 1; g <= G; ++g) gstart[g] = n;
    return;
  }
  __shared__ int h[1024];  // B <= 1024 by construction
  for (int i = t; i < B; i += TPB) h[i] = 0;
  __syncthreads();
  int lo = b * chunk, hi = min(lo + chunk, E);
  for (int e = lo + t; e < hi; e += TPB) atomicAdd(&h[dst[e] >> shift], 1);
  __syncthreads();
  for (int i = t; i < B; i += TPB) hist[i * NB1 + b] = h[i];
}

// ---------- two-level exclusive scan ----------
__global__ void scan_partial_kernel(const int* __restrict__ a, int* __restrict__ bsum,
                                    int n, int seg) {
  int b = blockIdx.x, t = threadIdx.x;
  int lo = b * seg, hi = min(lo + seg, n);
  int acc = 0;
  for (int i = lo + t; i < hi; i += TPB) acc += a[i];
  __shared__ int red[TPB];
  red[t] = acc;
  __syncthreads();
  for (int st = TPB / 2; st > 0; st >>= 1) {
    if (t < st) red[t] += red[t + st];
    __syncthreads();
  }
  if (t == 0) bsum[b] = red[0];
}

__global__ void scan_emit_kernel(int* __restrict__ a, const int* __restrict__ bsum,
                                 int n, int seg) {
  int b = blockIdx.x, t = threadIdx.x;
  int lo = b * seg, hi = min(lo + seg, n);
  __shared__ int cs[TPB];
  __shared__ int s_run;
  cs[t] = (t < b) ? bsum[t] : 0;  // only blocks before me
  __syncthreads();
  for (int st = TPB / 2; st > 0; st >>= 1) {
    if (t < st) cs[t] += cs[t + st];
    __syncthreads();
  }
  if (t == 0) s_run = cs[0];
  __syncthreads();
  for (int base = lo; base < hi; base += TPB) {
    int i = base + t;
    int v = (i < hi) ? a[i] : 0;
    cs[t] = v;
    __syncthreads();
    for (int off = 1; off < TPB; off <<= 1) {
      int u = (t >= off) ? cs[t - off] : 0;
      __syncthreads();
      cs[t] += u;
      __syncthreads();
    }
    if (i < hi) a[i] = s_run + cs[t] - v;  // exclusive
    __syncthreads();
    if (t == 0) s_run += cs[TPB - 1];
    __syncthreads();
  }
}

// ---------- phase 1b: scatter packed edges into bucket-contiguous epk ----------
__global__ void p1_scatter_kernel(const int* __restrict__ src, const int* __restrict__ dst,
                                  const int* __restrict__ hist, unsigned int* __restrict__ epk,
                                  int E, int chunk, int shift, int srcbits, int B) {
  __shared__ int cur[1024];
  int b = blockIdx.x, t = threadIdx.x;
  for (int i = t; i < B; i += TPB) cur[i] = hist[i * NB1 + b];
  __syncthreads();
  int lo = b * chunk, hi = min(lo + chunk, E);
  int span1 = (1 << shift) - 1;
  for (int e = lo + t; e < hi; e += TPB) {
    int d = dst[e];
    int pos = atomicAdd(&cur[d >> shift], 1);
    epk[pos] = ((unsigned int)(d & span1) << srcbits) | (unsigned int)src[e];
  }
}

// ---------- phase 2: per-bucket counting sort + rowptr/dinv/u0 emit ----------
__global__ __launch_bounds__(TPB) void p2_sort_kernel(
    const unsigned int* __restrict__ epk, const int* __restrict__ hist,
    const float2* __restrict__ x2,
    int* __restrict__ rowptr, float* __restrict__ dinv, float2* __restrict__ u0,
    int* __restrict__ esrc, int N, int E, int shift, int srcbits, int B) {
  int bkt = blockIdx.x, t = threadIdx.x;
  int span = 1 << shift;  // == 256 == TPB for N <= 262144
  unsigned int smask = (1u << srcbits) - 1u;
  int nb = bkt << shift;
  int bstart = hist[bkt * NB1];
  int bend = (bkt + 1 < B) ? hist[(bkt + 1) * NB1] : E;
  int bsize = bend - bstart;
  __shared__ int cnt[256];
  __shared__ int ex[256];
  __shared__ int ldata[P2CAP];
  __shared__ int lsrc[P2CAP];
  bool stage = (bsize <= P2CAP);
  if (t < span) cnt[t] = 0;
  __syncthreads();
  if (stage) {
    for (int i = t; i < bsize; i += TPB) ldata[i] = (int)epk[bstart + i];  // coalesced
    __syncthreads();
    for (int i = t; i < bsize; i += TPB)
      atomicAdd(&cnt[((unsigned int)ldata[i]) >> srcbits], 1);
  } else {
    for (int e = bstart + t; e < bend; e += TPB) atomicAdd(&cnt[epk[e] >> srcbits], 1);
  }
  __syncthreads();
  int v = (t < span) ? cnt[t] : 0;
  ex[t] = v;
  __syncthreads();
  for (int off = 1; off < 256; off <<= 1) {  // Hillis-Steele inclusive
    int u = (t >= off) ? ex[t - off] : 0;
    __syncthreads();
    ex[t] += u;
    __syncthreads();
  }
  int excl = ex[t] - v;  // exclusive scan value
  int node = nb + t;
  if (t < span && node < N) {
    rowptr[node] = bstart + excl;
    float dv = rsqrtf((float)v + 1.0f);  // +1 self-loop
    dinv[node] = dv;
    float2 xv = x2[node];
    u0[node] = make_float2(xv.x * dv, xv.y * dv);
  }
  if (bkt == 0 && t == 0) rowptr[N] = E;
  __syncthreads();
  if (t < span) cnt[t] = stage ? excl : bstart + excl;  // reuse cnt as cursor
  __syncthreads();
  if (stage) {
    for (int i = t; i < bsize; i += TPB) {
      unsigned int p = (unsigned int)ldata[i];
      int pos = atomicAdd(&cnt[p >> srcbits], 1);
      lsrc[pos] = (int)(p & smask);
    }
    __syncthreads();
    for (int i = t; i < bsize; i += TPB) esrc[bstart + i] = lsrc[i];  // coalesced
  } else {
    for (int e = bstart + t; e < bend; e += TPB) {
      unsigned int p = epk[e];
      int pos = atomicAdd(&cnt[p >> srcbits], 1);
      esrc[pos] = (int)(p & smask);
    }
  }
}

// Fused layer 1: dim-2 fp32 gather (4-way edge split, unroll-2), shuffle-
// combine, each split computes 8 of 32 features of
// u1 = dinv * relu(dinv*(W1@U0) + b1), written fp16.
__global__ void layer1_kernel(const float2* __restrict__ u0, const int* __restrict__ rowptr,
                              const int* __restrict__ esrc, const float* __restrict__ W1,
                              const float* __restrict__ b1, const float* __restrict__ dinv,
                              __half* __restrict__ u1_16, int n) {
  int tid = blockIdx.x * blockDim.x + threadIdx.x;
  int i = tid >> 2, split = tid & 3;
  if (i >= n) return;
  float ax = 0.f, ay = 0.f;
  if (split == 0) {  // self-loop
    float2 s = u0[i];
    ax = s.x; ay = s.y;
  }
  int r0 = rowptr[i], r1 = rowptr[i + 1];
  int e = r0 + split;
  while (e + 4 < r1) {  // unroll-2: two rows in flight
    int s0 = esrc[e], s1 = esrc[e + 4];
    float2 v0 = u0[s0];
    float2 v1 = u0[s1];
    ax += v0.x + v1.x;
    ay += v0.y + v1.y;
    e += 8;
  }
  if (e < r1) {
    float2 v = u0[esrc[e]];
    ax += v.x; ay += v.y;
  }
  ax += __shfl_xor(ax, 1, 64); ay += __shfl_xor(ay, 1, 64);
  ax += __shfl_xor(ax, 2, 64); ay += __shfl_xor(ay, 2, 64);
  float di = dinv[i];
  int f0 = split * 8;
  union { float4 f4[1]; __half h[8]; } oh;
#pragma unroll
  for (int k = 0; k < 8; ++k) {
    int f = f0 + k;
    float hv = fmaxf(di * (W1[f * 2 + 0] * ax + W1[f * 2 + 1] * ay) + b1[f], 0.f);
    oh.h[k] = __float2half(di * hv);
  }
  *(float4*)&u1_16[(size_t)i * 32 + f0] = oh.f4[0];  // 16B-aligned
}

// Dim-32 fp16 pull gather. 16 lanes/node: split = edge stripe (4), q =
// feature quad. Unroll-2 edge loop, shfl_xor combine. EPI: relu(di*acc+b)
// epilogue (layer 3); else raw sums (layer 2's U1).
template <bool EPI>
__global__ void gather32_kernel(const float4* __restrict__ a16,
                                const int* __restrict__ rowptr, const int* __restrict__ esrc,
                                const float* __restrict__ dinv, const float* __restrict__ b,
                                float4* __restrict__ out16, int n) {
  int tid = blockIdx.x * blockDim.x + threadIdx.x;
  int i = tid >> 4;
  int sub = tid & 15;
  int split = sub >> 2, q = sub & 3;
  if (i >= n) return;
  float acc[8] = {0.f, 0.f, 0.f, 0.f, 0.f, 0.f, 0.f, 0.f};
  auto addrow = [&](int s) {
    union { float4 f4; __half2 h2[4]; } u;
    u.f4 = a16[(size_t)s * 4 + q];
    float2 a0 = __half22float2(u.h2[0]);
    float2 a1 = __half22float2(u.h2[1]);
    float2 a2 = __half22float2(u.h2[2]);
    float2 a3 = __half22float2(u.h2[3]);
    acc[0] += a0.x; acc[1] += a0.y; acc[2] += a1.x; acc[3] += a1.y;
    acc[4] += a2.x; acc[5] += a2.y; acc[6] += a3.x; acc[7] += a3.y;
  };
  if (split == 0) addrow(i);  // self-loop
  int r0 = rowptr[i], r1 = rowptr[i + 1];
  int e = r0 + split;
  while (e + 4 < r1) {  // unroll-2: two rows in flight
    int s0 = esrc[e], s1 = esrc[e + 4];
    addrow(s0);
    addrow(s1);
    e += 8;
  }
  if (e < r1) addrow(esrc[e]);
#pragma unroll
  for (int k = 0; k < 8; ++k) acc[k] += __shfl_xor(acc[k], 4, 64);
#pragma unroll
  for (int k = 0; k < 8; ++k) acc[k] += __shfl_xor(acc[k], 8, 64);
  if (split != 0) return;
  if (EPI) {
    float di = dinv[i];
    const float4 bv0 = ((const float4*)b)[2 * q];
    const float4 bv1 = ((const float4*)b)[2 * q + 1];
    acc[0] = fmaxf(di * acc[0] + bv0.x, 0.f);
    acc[1] = fmaxf(di * acc[1] + bv0.y, 0.f);
    acc[2] = fmaxf(di * acc[2] + bv0.z, 0.f);
    acc[3] = fmaxf(di * acc[3] + bv0.w, 0.f);
    acc[4] = fmaxf(di * acc[4] + bv1.x, 0.f);
    acc[5] = fmaxf(di * acc[5] + bv1.y, 0.f);
    acc[6] = fmaxf(di * acc[6] + bv1.z, 0.f);
    acc[7] = fmaxf(di * acc[7] + bv1.w, 0.f);
  }
  union { float4 f4; __half2 h2[4]; } o;
  o.h2[0] = __floats2half2_rn(acc[0], acc[1]);
  o.h2[1] = __floats2half2_rn(acc[2], acc[3]);
  o.h2[2] = __floats2half2_rn(acc[4], acc[5]);
  o.h2[3] = __floats2half2_rn(acc[6], acc[7]);
  out16[(size_t)i * 4 + q] = o.f4;
}

// Fused layer-2+3 transform, register-tiled, 128 nodes/block; U1 fp16 in,
// g3 (dinv-prescaled) fp16 out.
__global__ __launch_bounds__(TPB) void t2t3_kernel(
    const float4* __restrict__ U1h, const float* __restrict__ W2, const float* __restrict__ b2,
    const float* __restrict__ W3, const float* __restrict__ dinv,
    __half* __restrict__ g3_16, int n) {
  constexpr int SN = 136;               // node-dim stride (16B-aligned fragments)
  __shared__ float U1l[32 * SN];        // [j][node]
  __shared__ float h2l[64 * SN];        // [k][node]
  __shared__ float W2l[32 * 68];        // [j][k], stride 68
  __shared__ float W3l[64 * 36];        // [j][k], stride 36
  __shared__ float dil[128];
  int t = threadIdx.x;
  int base = blockIdx.x * 128;
  for (int idx = t; idx < 2048; idx += TPB) {
    int k = idx >> 5, j = idx & 31;
    W2l[j * 68 + k] = W2[idx];
  }
  for (int idx = t; idx < 2048; idx += TPB) {
    int k = idx >> 6, j = idx & 63;
    W3l[j * 36 + k] = W3[idx];
  }
  if (t < 128) dil[t] = (base + t < n) ? dinv[base + t] : 0.f;
  for (int it = 0; it < 2; ++it) {
    int idx = it * 256 + t;
    int nl = idx >> 2, j0 = (idx & 3) * 8;
    int node = base + nl;
    union { float4 f4; __half2 h2[4]; } u;
    u.f4 = (node < n) ? U1h[(size_t)node * 4 + (idx & 3)]
                      : make_float4(0.f, 0.f, 0.f, 0.f);
#pragma unroll
    for (int k = 0; k < 4; ++k) {
      float2 p = __half22float2(u.h2[k]);
      U1l[(j0 + 2 * k + 0) * SN + nl] = p.x;
      U1l[(j0 + 2 * k + 1) * SN + nl] = p.y;
    }
  }
  __syncthreads();
  {  // phase 1: h2l[k][n] over 128n x 64k; thread 8n x 4k
    int a = t & 15, bb = t >> 4;
    int n0 = a * 8, k0 = bb * 4;
    float acc[4][8];
#pragma unroll
    for (int kk = 0; kk < 4; ++kk)
#pragma unroll
      for (int nn = 0; nn < 8; ++nn) acc[kk][nn] = 0.f;
#pragma unroll 8
    for (int j = 0; j < 32; ++j) {
      float4 ua = *(const float4*)&U1l[j * SN + n0];
      float4 ub = *(const float4*)&U1l[j * SN + n0 + 4];
      float4 w = *(const float4*)&W2l[j * 68 + k0];
      float un[8] = {ua.x, ua.y, ua.z, ua.w, ub.x, ub.y, ub.z, ub.w};
      float wk[4] = {w.x, w.y, w.z, w.w};
#pragma unroll
      for (int kk = 0; kk < 4; ++kk)
#pragma unroll
        for (int nn = 0; nn < 8; ++nn) acc[kk][nn] += un[nn] * wk[kk];
    }
    float4 bv = ((const float4*)b2)[bb];
    float bk[4] = {bv.x, bv.y, bv.z, bv.w};
#pragma unroll
    for (int kk = 0; kk < 4; ++kk) {
      float o[8];
#pragma unroll
      for (int nn = 0; nn < 8; ++nn)
        o[nn] = fmaxf(dil[n0 + nn] * acc[kk][nn] + bk[kk], 0.f);
      *(float4*)&h2l[(k0 + kk) * SN + n0] = make_float4(o[0], o[1], o[2], o[3]);
      *(float4*)&h2l[(k0 + kk) * SN + n0 + 4] = make_float4(o[4], o[5], o[6], o[7]);
    }
  }
  __syncthreads();
  {  // phase 2: g3[n][k] over 128n x 32k; thread 8n x 2k
    int a = t & 15, bb = t >> 4;
    int n0 = a * 8, k0 = bb * 2;
    float acc[2][8];
#pragma unroll
    for (int kk = 0; kk < 2; ++kk)
#pragma unroll
      for (int nn = 0; nn < 8; ++nn) acc[kk][nn] = 0.f;
#pragma unroll 8
    for (int j = 0; j < 64; ++j) {
      float4 ua = *(const float4*)&h2l[j * SN + n0];
      float4 ub = *(const float4*)&h2l[j * SN + n0 + 4];
      float w0 = W3l[j * 36 + k0];
      float w1 = W3l[j * 36 + k0 + 1];
      float un[8] = {ua.x, ua.y, ua.z, ua.w, ub.x, ub.y, ub.z, ub.w};
#pragma unroll
      for (int nn = 0; nn < 8; ++nn) {
        acc[0][nn] += un[nn] * w0;
        acc[1][nn] += un[nn] * w1;
      }
    }
#pragma unroll
    for (int nn = 0; nn < 8; ++nn) {
      int node = base + n0 + nn;
      if (node < n) {
        float di = dil[n0 + nn];
        __half2 hv = __floats2half2_rn(di * acc[0][nn], di * acc[1][nn]);
        *(__half2*)&g3_16[(size_t)node * 32 + k0] = hv;
      }
    }
  }
}

// Block per graph: mean-pool fp16 h3 over the graph's node range, then FC.
// half2 loads, 16 nodes in flight (t = nl*16 + f2).
__global__ void poolfc_kernel(const __half2* __restrict__ h3, const int* __restrict__ gstart,
                              const float* __restrict__ Wfc, const float* __restrict__ bfc,
                              float* __restrict__ out) {
  int gi = blockIdx.x;
  int s = gstart[gi], e = gstart[gi + 1];
  int t = threadIdx.x;
  int nl = t >> 4, f2 = t & 15;
  float ax = 0.f, ay = 0.f;
  for (int i = s + nl; i < e; i += 16) {
    float2 v = __half22float2(h3[(size_t)i * 16 + f2]);
    ax += v.x; ay += v.y;
  }
  __shared__ float redx[256], redy[256];
  redx[t] = ax; redy[t] = ay;
  __syncthreads();
  for (int st = 128; st >= 16; st >>= 1) {
    if (t < st) { redx[t] += redx[t + st]; redy[t] += redy[t + st]; }
    __syncthreads();
  }
  if (t < 16) {
    float cnt = fmaxf((float)(e - s), 1.f);
    float v = (redx[t] / cnt) * Wfc[2 * t] + (redy[t] / cnt) * Wfc[2 * t + 1];
    for (int o = 8; o; o >>= 1) v += __shfl_down(v, o, 16);
    if (t == 0) out[gi] = v + bfc[0];
  }
}

extern "C" void kernel_launch(void* const* d_in, const int* in_sizes, int n_in,
                              void* d_out, int out_size, void* d_ws, size_t ws_size,
                              hipStream_t stream) {
  const float* x     = (const float*)d_in[0];
  const int*   ei    = (const int*)d_in[1];  // int32 on device
  const int*   batch = (const int*)d_in[2];
  const float* W1    = (const float*)d_in[3];
  const float* b1    = (const float*)d_in[4];
  const float* W2    = (const float*)d_in[5];
  const float* b2    = (const float*)d_in[6];
  const float* W3    = (const float*)d_in[7];
  const float* b3    = (const float*)d_in[8];
  const float* Wfc   = (const float*)d_in[9];
  const float* bfc   = (const float*)d_in[10];
  float* out = (float*)d_out;

  const int N = in_sizes[0] / 2;
  const int E = in_sizes[1] / 2;
  const int G = out_size;  // 512
  const int* src = ei;
  const int* dst = ei + E;

  // Bucket geometry: span = 1<<shift, B <= 1024, span <= 256 (p2 LDS width).
  int shift = 8;
  while ((((N + (1 << shift) - 1) >> shift)) > 1024) ++shift;
  const int B = (N + (1 << shift) - 1) >> shift;
  const int srcbits = 32 - shift;
  const int chunkE = (E + NB1 - 1) / NB1;
  const int M = B * NB1;
  const int segM = (M + NB_SCAN - 1) / NB_SCAN;

  char* ws = (char*)d_ws;
  size_t off = 0;
  auto alloc = [&](size_t bytes) -> char* {
    char* p = ws + off;
    off += (bytes + 255) & ~(size_t)255;
    return p;
  };
  float*        dinv   = (float*)alloc((size_t)N * 4);
  int*          rowptr = (int*)alloc((size_t)(N + 1) * 4);
  int*          esrc   = (int*)alloc((size_t)E * 4);
  int*          gstart = (int*)alloc((size_t)(G + 1) * 4);
  int*          hist   = (int*)alloc((size_t)M * 4);
  int*          bsum   = (int*)alloc((size_t)NB_SCAN * 4);
  unsigned int* epk    = (unsigned int*)alloc((size_t)E * 4);
  float2*       u0     = (float2*)alloc((size_t)N * 8);
  __half*       u1_16  = (__half*)alloc((size_t)N * 32 * 2);
  __half*       U1h    = (__half*)alloc((size_t)N * 32 * 2);
  __half*       g3_16  = (__half*)alloc((size_t)N * 32 * 2);
  __half*       hA16   = (__half*)alloc((size_t)N * 32 * 2);  // h3

  // --- structure build: bucketed counting sort (no global atomics) ---
  const int gptrBlocks = (N + TPB - 1) / TPB;
  p1_hist_gptr_kernel<<<NB1 + gptrBlocks, TPB, 0, stream>>>(dst, hist, E, chunkE, shift, B,
                                                            batch, gstart, N, G);
  scan_partial_kernel<<<NB_SCAN, TPB, 0, stream>>>(hist, bsum, M, segM);
  scan_emit_kernel<<<NB_SCAN, TPB, 0, stream>>>(hist, bsum, M, segM);
  p1_scatter_kernel<<<NB1, TPB, 0, stream>>>(src, dst, hist, epk, E, chunkE, shift, srcbits, B);
  p2_sort_kernel<<<B, TPB, 0, stream>>>(epk, hist, (const float2*)x, rowptr, dinv, u0, esrc,
                                        N, E, shift, srcbits, B);

  // --- layer 1: fused dim-2 gather + transform (fp16 out) ---
  layer1_kernel<<<((size_t)N * 4 + TPB - 1) / TPB, TPB, 0, stream>>>(
      u0, rowptr, esrc, W1, b1, dinv, u1_16, N);

  // --- layer 2: dim-32 pull gather -> raw sums U1h, then 128-node t2t3 -> g3 ---
  gather32_kernel<false><<<((size_t)N * 16 + TPB - 1) / TPB, TPB, 0, stream>>>(
      (const float4*)u1_16, rowptr, esrc, dinv, b2, (float4*)U1h, N);
  t2t3_kernel<<<(N + 127) / 128, TPB, 0, stream>>>(
      (const float4*)U1h, W2, b2, W3, dinv, g3_16, N);

  // --- layer 3: dim-32 pull gather + relu epilogue -> fp16 h3 ---
  gather32_kernel<true><<<((size_t)N * 16 + TPB - 1) / TPB, TPB, 0, stream>>>(
      (const float4*)g3_16, rowptr, esrc, dinv, b3, (float4*)hA16, N);

  // --- pool + fc ---
  poolfc_kernel<<<G, 256, 0, stream>>>((const __half2*)hA16, gstart, Wfc, bfc, out);
}